// Round 7
// baseline (282.325 us; speedup 1.0000x reference)
//
#include <hip/hip_runtime.h>
#include <hip/hip_fp16.h>
#include <math.h>

// Problem: B=2, S=2048, D=1024, H=16, HD=64, causal attention + RoPE.
// ALL inputs fp32 (reference dtypes), output fp32.
#define B_  2
#define S_  2048
#define D_  1024
#define H_  16
#define HD_ 64

typedef _Float16  f16;
typedef __attribute__((ext_vector_type(8))) _Float16 f16x8;
typedef __attribute__((ext_vector_type(4))) _Float16 f16x4;
typedef __attribute__((ext_vector_type(4))) float    f32x4;

#define LOG2E 1.4426950408889634f
#define L2_10000_DIV32 0.41524101186092029f  /* log2(10000)/32 */
#define PS 72   /* attn LDS row stride (f16) */
#define GS 36   /* GEMM LDS row stride (f16), BK=32 + 4 pad: 2-way max conflict */

__device__ __forceinline__ float fin(float v) { return (v == v) ? v : 0.0f; }

__device__ __forceinline__ f16x8 cvt8(const float* p) {
  float4 a = *(const float4*)p;
  float4 b = *(const float4*)(p + 4);
  f16x8 h;
  h[0] = (f16)a.x; h[1] = (f16)a.y; h[2] = (f16)a.z; h[3] = (f16)a.w;
  h[4] = (f16)b.x; h[5] = (f16)b.y; h[6] = (f16)b.z; h[7] = (f16)b.w;
  return h;
}

// ---------------------------------------------------------------------------
// Kernel 0: one-shot fp32 -> f16 conversion of weights (and x when ws allows).
// ---------------------------------------------------------------------------
__global__ void __launch_bounds__(256)
k_cvt3(const float* __restrict__ wq, const float* __restrict__ wo,
       const float* __restrict__ x,
       f16* __restrict__ wqh, f16* __restrict__ woh, f16* __restrict__ xh,
       int doX)
{
  const int NWQ = 3 * D_ * D_ / 4, NWO = D_ * D_ / 4, NX = B_ * S_ * D_ / 4;
  const int n = NWQ + NWO + (doX ? NX : 0);
  for (int i = blockIdx.x * 256 + threadIdx.x; i < n; i += gridDim.x * 256) {
    const float* src; f16* dst; int j;
    if (i < NWQ)            { src = wq; dst = wqh; j = i; }
    else if (i < NWQ + NWO) { src = wo; dst = woh; j = i - NWQ; }
    else                    { src = x;  dst = xh;  j = i - NWQ - NWO; }
    float4 v = ((const float4*)src)[j];
    f16x4 h = {(f16)v.x, (f16)v.y, (f16)v.z, (f16)v.w};
    ((f16x4*)dst)[j] = h;
  }
}

// ---------------------------------------------------------------------------
// Kernel 1: qkv = x @ w_qkv^T + RoPE epilogue. k_attn2-style pipeline:
// 128x128 tile, BK=32 (32 iters), double-buffered padded LDS (GS=36),
// register prefetch of next slab during MFMA, ONE barrier per iteration.
// ---------------------------------------------------------------------------
template <bool XF16>
__global__ void __launch_bounds__(256)
k_qkv2(const float* __restrict__ xf, const f16* __restrict__ xh,
       const f16* __restrict__ wqh,
       f16* __restrict__ Qb, f16* __restrict__ Kb, f16* __restrict__ Vt)
{
  __shared__ __align__(16) f16 As[2][128 * GS];
  __shared__ __align__(16) f16 Bs[2][128 * GS];
  const int t = threadIdx.x;
  const int w = t >> 6;
  const int lane = t & 63;
  const int ll = lane & 15;
  const int quad = lane >> 4;
  const int wm = w >> 1, wn = w & 1;
  const int row0 = blockIdx.y * 128;
  const int col0 = blockIdx.x * 128;

  const int srow = t >> 2;          // 0..63
  const int sc   = (t & 3) * 8;     // 0,8,16,24 (f16 within 32-col slab)

  const f32x4 fz = {0.f, 0.f, 0.f, 0.f};
  f32x4 acc[4][4];
#pragma unroll
  for (int i = 0; i < 4; ++i)
#pragma unroll
    for (int j = 0; j < 4; ++j) acc[i][j] = fz;

  const float* gaf = xf  + (size_t)(row0 + srow) * D_ + sc;
  const f16*   gah = xh  + (size_t)(row0 + srow) * D_ + sc;
  const f16*   gb  = wqh + (size_t)(col0 + srow) * D_ + sc;

  f16x8 pa[2], pb[2];
  // stage iter 0
#pragma unroll
  for (int i = 0; i < 2; ++i) {
    pa[i] = XF16 ? *(const f16x8*)(gah + (size_t)i * 64 * D_)
                 : cvt8(gaf + (size_t)i * 64 * D_);
    pb[i] = *(const f16x8*)(gb + (size_t)i * 64 * D_);
  }
#pragma unroll
  for (int i = 0; i < 2; ++i) {
    *(f16x8*)&As[0][(i * 64 + srow) * GS + sc] = pa[i];
    *(f16x8*)&Bs[0][(i * 64 + srow) * GS + sc] = pb[i];
  }
  __syncthreads();

  for (int kt = 0; kt < 32; ++kt) {
    const int cur = kt & 1;
    const bool pre = (kt < 31);
    if (pre) {
      const int ko = (kt + 1) * 32;
#pragma unroll
      for (int i = 0; i < 2; ++i) {
        pa[i] = XF16 ? *(const f16x8*)(gah + (size_t)i * 64 * D_ + ko)
                     : cvt8(gaf + (size_t)i * 64 * D_ + ko);
        pb[i] = *(const f16x8*)(gb + (size_t)i * 64 * D_ + ko);
      }
    }
    const f16* Ac = As[cur];
    const f16* Bc = Bs[cur];
    f16x8 a[4], b[4];
#pragma unroll
    for (int mt = 0; mt < 4; ++mt)
      a[mt] = *(const f16x8*)&Ac[(wm * 64 + mt * 16 + ll) * GS + quad * 8];
#pragma unroll
    for (int nt = 0; nt < 4; ++nt)
      b[nt] = *(const f16x8*)&Bc[(wn * 64 + nt * 16 + ll) * GS + quad * 8];
#pragma unroll
    for (int mt = 0; mt < 4; ++mt)
#pragma unroll
      for (int nt = 0; nt < 4; ++nt)
        acc[mt][nt] = __builtin_amdgcn_mfma_f32_16x16x32_f16(
            a[mt], b[nt], acc[mt][nt], 0, 0, 0);
    if (pre) {
#pragma unroll
      for (int i = 0; i < 2; ++i) {
        *(f16x8*)&As[1 - cur][(i * 64 + srow) * GS + sc] = pa[i];
        *(f16x8*)&Bs[1 - cur][(i * 64 + srow) * GS + sc] = pb[i];
      }
    }
    __syncthreads();
  }

  // Epilogue (verified r4-r6). C/D layout: col = ll, row = quad*4 + r.
  const int h3 = (col0 >> 6) + wn;
  if (h3 < 32) {
    f16* dst = (h3 < 16) ? Qb : Kb;
    const int h = (h3 < 16) ? h3 : h3 - 16;
    const float th0 = exp2f(-(float)ll * L2_10000_DIV32);
    const float th1 = exp2f(-(float)(16 + ll) * L2_10000_DIV32);
#pragma unroll
    for (int mt = 0; mt < 4; ++mt) {
#pragma unroll
      for (int r = 0; r < 4; ++r) {
        const int row = row0 + wm * 64 + mt * 16 + quad * 4 + r;
        const int b = row >> 11;
        const int p = row & (S_ - 1);
        f16* base = dst + ((size_t)(b * H_ + h) * S_ + p) * HD_;
        const float fp = (float)p;
        float s0, c0, s1, c1;
        sincosf(fp * th0, &s0, &c0);
        sincosf(fp * th1, &s1, &c1);
        {
          float x1 = acc[mt][0][r], x2 = acc[mt][2][r];
          base[ll]      = (f16)fin(x1 * c0 - x2 * s0);
          base[ll + 32] = (f16)fin(x2 * c0 + x1 * s0);
        }
        {
          float x1 = acc[mt][1][r], x2 = acc[mt][3][r];
          base[16 + ll]      = (f16)fin(x1 * c1 - x2 * s1);
          base[16 + ll + 32] = (f16)fin(x2 * c1 + x1 * s1);
        }
      }
    }
  } else {
    const int hv = h3 - 32;
#pragma unroll
    for (int mt = 0; mt < 4; ++mt)
#pragma unroll
      for (int nt = 0; nt < 4; ++nt)
#pragma unroll
        for (int r = 0; r < 4; ++r) {
          const int row = row0 + wm * 64 + mt * 16 + quad * 4 + r;
          const int b = row >> 11;
          const int p = row & (S_ - 1);
          const int dd = nt * 16 + ll;
          Vt[((size_t)(b * H_ + hv) * HD_ + dd) * S_ + p] = (f16)fin(acc[mt][nt][r]);
        }
  }
}

// ---------------------------------------------------------------------------
// k_attn2: causal flash attention (r5/r6, verified). O in place over Qb.
// ---------------------------------------------------------------------------
__device__ __forceinline__ void softmax_tile(
    f32x4 sc[4], bool diag, int qloc, int ll, int quad,
    float& mrun, float& lrun, float& alpha, f16* Pt)
{
  float pm = -3.0e4f;
#pragma unroll
  for (int nt = 0; nt < 4; ++nt)
#pragma unroll
    for (int r = 0; r < 4; ++r) {
      float s = sc[nt][r];
      s = (s == s) ? s : -3.0e4f;
      if (diag && (nt * 16 + quad * 4 + r) > qloc) s = -3.0e4f;
      sc[nt][r] = s;
      pm = fmaxf(pm, s);
    }
  pm = fmaxf(pm, __shfl_xor(pm, 16));
  pm = fmaxf(pm, __shfl_xor(pm, 32));
  const float mn = fmaxf(mrun, pm);
  alpha = exp2f(mrun - mn);
  mrun = mn;
  float ps = 0.f;
#pragma unroll
  for (int nt = 0; nt < 4; ++nt) {
    f16x4 pk;
#pragma unroll
    for (int r = 0; r < 4; ++r) {
      float p = exp2f(sc[nt][r] - mn);
      ps += p;
      pk[r] = (f16)p;
    }
    *(f16x4*)&Pt[ll * PS + nt * 16 + quad * 4] = pk;
  }
  ps += __shfl_xor(ps, 16);
  ps += __shfl_xor(ps, 32);
  lrun = lrun * alpha + ps;
}

__device__ __forceinline__ void write_o(
    f32x4 acco[4], float lrun, f16* Pt, int ll, int quad, int w,
    int qt, size_t bh, f16* Ob)
{
  const float inv = 1.0f / fmaxf(lrun, 1e-30f);
#pragma unroll
  for (int dg = 0; dg < 4; ++dg) {
    f16x4 ov;
#pragma unroll
    for (int r = 0; r < 4; ++r) ov[r] = (f16)fin(acco[dg][r] * inv);
    *(f16x4*)&Pt[ll * PS + dg * 16 + quad * 4] = ov;
  }
#pragma unroll
  for (int s2 = 0; s2 < 2; ++s2) {
    f16x8 o = *(const f16x8*)&Pt[ll * PS + (quad + 4 * s2) * 8];
    const size_t row = bh * S_ + qt * 64 + w * 16 + ll;
    *(f16x8*)&Ob[row * HD_ + (quad + 4 * s2) * 8] = o;
  }
}

__global__ void __launch_bounds__(256, 2)
k_attn2(const f16* Qb, const f16* __restrict__ Kb,
        const f16* __restrict__ Vt, f16* Ob)
{
  __shared__ __align__(16) f16 Qs[128 * PS];
  __shared__ __align__(16) f16 Ks[2][64 * PS];
  __shared__ __align__(16) f16 Vs[2][64 * PS];
  __shared__ __align__(16) f16 Ps[4][16 * PS];

  const int t = threadIdx.x;
  const int w = t >> 6;
  const int lane = t & 63;
  const int ll = lane & 15;
  const int quad = lane >> 4;
  const int qtA = blockIdx.x;
  const int qtB = 31 - qtA;
  const int h = blockIdx.y;
  const int b = blockIdx.z;
  const size_t bh = (size_t)b * H_ + h;
  const f16* Qg = Qb + bh * S_ * HD_;
  const f16* Kg = Kb + bh * S_ * HD_;
  const f16* Vg = Vt + bh * HD_ * S_;

  {
    const int r = t >> 1;
    const int c0 = (t & 1) * 32;
    const int grow = (r < 64) ? (qtA * 64 + r) : (qtB * 64 + r - 64);
    const f16 hsc = (f16)(0.125f * LOG2E);
#pragma unroll
    for (int j = 0; j < 4; ++j) {
      f16x8 v = *(const f16x8*)(Qg + (size_t)grow * HD_ + c0 + j * 8);
#pragma unroll
      for (int e = 0; e < 8; ++e) v[e] *= hsc;
      *(f16x8*)&Qs[r * PS + c0 + j * 8] = v;
    }
  }
  {
    const int r = t >> 2;
    const int c = (t & 3) * 16;
    f16x8 a0 = *(const f16x8*)(Kg + (size_t)r * HD_ + c);
    f16x8 a1 = *(const f16x8*)(Kg + (size_t)r * HD_ + c + 8);
    f16x8 b0 = *(const f16x8*)(Vg + (size_t)r * S_ + c);
    f16x8 b1 = *(const f16x8*)(Vg + (size_t)r * S_ + c + 8);
    *(f16x8*)&Ks[0][r * PS + c]     = a0;
    *(f16x8*)&Ks[0][r * PS + c + 8] = a1;
    *(f16x8*)&Vs[0][r * PS + c]     = b0;
    *(f16x8*)&Vs[0][r * PS + c + 8] = b1;
  }
  __syncthreads();

  const f32x4 fz = {0.f, 0.f, 0.f, 0.f};
  f32x4 accoA[4], accoB[4];
#pragma unroll
  for (int i = 0; i < 4; ++i) { accoA[i] = fz; accoB[i] = fz; }
  float mA = -3.0e4f, lA = 0.f, mB = -3.0e4f, lB = 0.f;
  const int qloc = w * 16 + ll;
  f16* Pt = &Ps[w][0];

  for (int kt = 0; kt <= qtB; ++kt) {
    const int cur = kt & 1;
    const bool pre = (kt < qtB);
    const int sr = t >> 2, scc = (t & 3) * 16;
    f16x8 nk0, nk1, nv0, nv1;
    if (pre) {
      const int kn = (kt + 1) * 64;
      nk0 = *(const f16x8*)(Kg + (size_t)(kn + sr) * HD_ + scc);
      nk1 = *(const f16x8*)(Kg + (size_t)(kn + sr) * HD_ + scc + 8);
      nv0 = *(const f16x8*)(Vg + (size_t)sr * S_ + kn + scc);
      nv1 = *(const f16x8*)(Vg + (size_t)sr * S_ + kn + scc + 8);
    }
    const f16* Kc = Ks[cur];
    const f16* Vc = Vs[cur];
    const bool doA = (kt <= qtA);

    f16x8 ak[2][4];
#pragma unroll
    for (int k2 = 0; k2 < 2; ++k2)
#pragma unroll
      for (int nt = 0; nt < 4; ++nt)
        ak[k2][nt] = *(const f16x8*)&Kc[(nt * 16 + ll) * PS + k2 * 32 + quad * 8];

    f32x4 sB[4] = {fz, fz, fz, fz};
#pragma unroll
    for (int k2 = 0; k2 < 2; ++k2) {
      f16x8 bq = *(const f16x8*)&Qs[(64 + w * 16 + ll) * PS + k2 * 32 + quad * 8];
#pragma unroll
      for (int nt = 0; nt < 4; ++nt)
        sB[nt] = __builtin_amdgcn_mfma_f32_16x16x32_f16(ak[k2][nt], bq, sB[nt], 0, 0, 0);
    }
    f32x4 sA[4] = {fz, fz, fz, fz};
    if (doA) {
#pragma unroll
      for (int k2 = 0; k2 < 2; ++k2) {
        f16x8 bq = *(const f16x8*)&Qs[(w * 16 + ll) * PS + k2 * 32 + quad * 8];
#pragma unroll
        for (int nt = 0; nt < 4; ++nt)
          sA[nt] = __builtin_amdgcn_mfma_f32_16x16x32_f16(ak[k2][nt], bq, sA[nt], 0, 0, 0);
      }
    }

    f16x8 av[2][4];
#pragma unroll
    for (int k2 = 0; k2 < 2; ++k2)
#pragma unroll
      for (int dg = 0; dg < 4; ++dg)
        av[k2][dg] = *(const f16x8*)&Vc[(dg * 16 + ll) * PS + k2 * 32 + quad * 8];

    float alpha;
    if (doA) {
      softmax_tile(sA, kt == qtA, qloc, ll, quad, mA, lA, alpha, Pt);
#pragma unroll
      for (int dg = 0; dg < 4; ++dg)
#pragma unroll
        for (int r = 0; r < 4; ++r) accoA[dg][r] *= alpha;
#pragma unroll
      for (int k2 = 0; k2 < 2; ++k2) {
        f16x8 bp = *(const f16x8*)&Pt[ll * PS + k2 * 32 + quad * 8];
#pragma unroll
        for (int dg = 0; dg < 4; ++dg)
          accoA[dg] = __builtin_amdgcn_mfma_f32_16x16x32_f16(av[k2][dg], bp, accoA[dg], 0, 0, 0);
      }
    }
    {
      softmax_tile(sB, kt == qtB, qloc, ll, quad, mB, lB, alpha, Pt);
#pragma unroll
      for (int dg = 0; dg < 4; ++dg)
#pragma unroll
        for (int r = 0; r < 4; ++r) accoB[dg][r] *= alpha;
#pragma unroll
      for (int k2 = 0; k2 < 2; ++k2) {
        f16x8 bp = *(const f16x8*)&Pt[ll * PS + k2 * 32 + quad * 8];
#pragma unroll
        for (int dg = 0; dg < 4; ++dg)
          accoB[dg] = __builtin_amdgcn_mfma_f32_16x16x32_f16(av[k2][dg], bp, accoB[dg], 0, 0, 0);
      }
    }

    if (pre) {
      *(f16x8*)&Ks[1 - cur][sr * PS + scc]     = nk0;
      *(f16x8*)&Ks[1 - cur][sr * PS + scc + 8] = nk1;
      *(f16x8*)&Vs[1 - cur][sr * PS + scc]     = nv0;
      *(f16x8*)&Vs[1 - cur][sr * PS + scc + 8] = nv1;
    }
    __syncthreads();
  }

  write_o(accoA, lA, Pt, ll, quad, w, qtA, bh, Ob);
  write_o(accoB, lB, Pt, ll, quad, w, qtB, bh, Ob);
}

// ---------------------------------------------------------------------------
// Kernel 3: out = O @ w_out^T + b_out. Same pipelined structure as k_qkv2.
// A = O (f16, B,H,S,HD layout; BK=32 spans half a head, rows contiguous).
// ---------------------------------------------------------------------------
__global__ void __launch_bounds__(256)
k_out2(const f16* __restrict__ Ob, const f16* __restrict__ Wh,
       const float* __restrict__ bias, float* __restrict__ out)
{
  __shared__ __align__(16) f16 As[2][128 * GS];
  __shared__ __align__(16) f16 Bs[2][128 * GS];
  const int t = threadIdx.x;
  const int w = t >> 6;
  const int lane = t & 63;
  const int ll = lane & 15;
  const int quad = lane >> 4;
  const int wm = w >> 1, wn = w & 1;
  const int row0 = blockIdx.y * 128;
  const int col0 = blockIdx.x * 128;
  const int bb = row0 >> 11;
  const int s0 = row0 & (S_ - 1);

  const int srow = t >> 2;
  const int sc   = (t & 3) * 8;

  const f32x4 fz = {0.f, 0.f, 0.f, 0.f};
  f32x4 acc[4][4];
#pragma unroll
  for (int i = 0; i < 4; ++i)
#pragma unroll
    for (int j = 0; j < 4; ++j) acc[i][j] = fz;

  const f16* gb = Wh + (size_t)(col0 + srow) * D_ + sc;
  // A slab address for K-iter kt: head = kt>>1, col offset (kt&1)*32.
  const f16* gaBase = Ob + ((size_t)bb * H_ * S_ + s0 + srow) * HD_ + sc;

  f16x8 pa[2], pb[2];
#pragma unroll
  for (int i = 0; i < 2; ++i) {
    pa[i] = *(const f16x8*)(gaBase + (size_t)i * 64 * HD_);
    pb[i] = *(const f16x8*)(gb + (size_t)i * 64 * D_);
  }
#pragma unroll
  for (int i = 0; i < 2; ++i) {
    *(f16x8*)&As[0][(i * 64 + srow) * GS + sc] = pa[i];
    *(f16x8*)&Bs[0][(i * 64 + srow) * GS + sc] = pb[i];
  }
  __syncthreads();

  for (int kt = 0; kt < 32; ++kt) {
    const int cur = kt & 1;
    const bool pre = (kt < 31);
    if (pre) {
      const int kn = kt + 1;
      const size_t aoff = (size_t)(kn >> 1) * S_ * HD_ + (kn & 1) * 32;
      const int ko = kn * 32;
#pragma unroll
      for (int i = 0; i < 2; ++i) {
        pa[i] = *(const f16x8*)(gaBase + aoff + (size_t)i * 64 * HD_);
        pb[i] = *(const f16x8*)(gb + (size_t)i * 64 * D_ + ko);
      }
    }
    const f16* Ac = As[cur];
    const f16* Bc = Bs[cur];
    f16x8 a[4], b[4];
#pragma unroll
    for (int mt = 0; mt < 4; ++mt)
      a[mt] = *(const f16x8*)&Ac[(wm * 64 + mt * 16 + ll) * GS + quad * 8];
#pragma unroll
    for (int nt = 0; nt < 4; ++nt)
      b[nt] = *(const f16x8*)&Bc[(wn * 64 + nt * 16 + ll) * GS + quad * 8];
#pragma unroll
    for (int mt = 0; mt < 4; ++mt)
#pragma unroll
      for (int nt = 0; nt < 4; ++nt)
        acc[mt][nt] = __builtin_amdgcn_mfma_f32_16x16x32_f16(
            a[mt], b[nt], acc[mt][nt], 0, 0, 0);
    if (pre) {
#pragma unroll
      for (int i = 0; i < 2; ++i) {
        *(f16x8*)&As[1 - cur][(i * 64 + srow) * GS + sc] = pa[i];
        *(f16x8*)&Bs[1 - cur][(i * 64 + srow) * GS + sc] = pb[i];
      }
    }
    __syncthreads();
  }

#pragma unroll
  for (int mt = 0; mt < 4; ++mt)
#pragma unroll
    for (int r = 0; r < 4; ++r) {
      const int row = row0 + wm * 64 + mt * 16 + quad * 4 + r;
#pragma unroll
      for (int nt = 0; nt < 4; ++nt) {
        const int col = col0 + wn * 64 + nt * 16 + ll;
        out[(size_t)row * D_ + col] = fin(acc[mt][nt][r] + bias[col]);
      }
    }
}

// ---------------------------------------------------------------------------
extern "C" void kernel_launch(void* const* d_in, const int* in_sizes, int n_in,
                              void* d_out, int out_size, void* d_ws, size_t ws_size,
                              hipStream_t stream) {
  const float* x    = (const float*)d_in[0];
  const float* wqkv = (const float*)d_in[1];
  const float* wout = (const float*)d_in[2];
  const float* bout = (const float*)d_in[3];
  float* out = (float*)d_out;

  // ws: wqkvh 6M | Qb/O 8M | Kb 8M | Vt 8M | woh 2M | xh 8M (if big ws)
  char* ws = (char*)d_ws;
  f16* wqh = (f16*)(ws);
  f16* Qb  = (f16*)(ws + 6291456);
  f16* Kb  = (f16*)(ws + 14680064);
  f16* Vt  = (f16*)(ws + 23068672);
  f16* woh = (f16*)(ws + 31457280);
  const bool bigws = ws_size >= (size_t)41943040;
  f16* xh  = (f16*)(ws + 33554432);

  k_cvt3<<<2048, 256, 0, stream>>>(wqkv, wout, x, wqh, woh, xh, bigws ? 1 : 0);
  if (bigws)
    k_qkv2<true><<<dim3(3 * D_ / 128, (B_ * S_) / 128), 256, 0, stream>>>(
        x, xh, wqh, Qb, Kb, Vt);
  else
    k_qkv2<false><<<dim3(3 * D_ / 128, (B_ * S_) / 128), 256, 0, stream>>>(
        x, xh, wqh, Qb, Kb, Vt);
  k_attn2<<<dim3(16, H_, B_), 256, 0, stream>>>(Qb, Kb, Vt, Qb /* O in place */);
  k_out2<<<dim3(D_ / 128, (B_ * S_) / 128), 256, 0, stream>>>(
      Qb, woh, bout, out);
}

// Round 8
// 195.356 us; speedup vs baseline: 1.4452x; 1.4452x over previous
//
#include <hip/hip_runtime.h>
#include <hip/hip_fp16.h>
#include <math.h>

// Problem: B=2, S=2048, D=1024, H=16, HD=64, causal attention + RoPE.
// ALL inputs fp32 (reference dtypes), output fp32.
#define B_  2
#define S_  2048
#define D_  1024
#define H_  16
#define HD_ 64

typedef _Float16  f16;
typedef __attribute__((ext_vector_type(8))) _Float16 f16x8;
typedef __attribute__((ext_vector_type(4))) _Float16 f16x4;
typedef __attribute__((ext_vector_type(4))) float    f32x4;

#define LOG2E 1.4426950408889634f
#define L2_10000_DIV32 0.41524101186092029f  /* log2(10000)/32 */
#define PS 72   /* LDS row stride (f16): bank=(4*ll+4*quad)%32 -> uniform */

__device__ __forceinline__ float fin(float v) { return (v == v) ? v : 0.0f; }

__device__ __forceinline__ f16x8 cvt8(const float* p) {
  float4 a = *(const float4*)p;
  float4 b = *(const float4*)(p + 4);
  f16x8 h;
  h[0] = (f16)a.x; h[1] = (f16)a.y; h[2] = (f16)a.z; h[3] = (f16)a.w;
  h[4] = (f16)b.x; h[5] = (f16)b.y; h[6] = (f16)b.z; h[7] = (f16)b.w;
  return h;
}

// ---------------------------------------------------------------------------
// Kernel 0: one-shot fp32 -> f16 conversion of weights (and x when ws allows).
// ---------------------------------------------------------------------------
__global__ void __launch_bounds__(256)
k_cvt3(const float* __restrict__ wq, const float* __restrict__ wo,
       const float* __restrict__ x,
       f16* __restrict__ wqh, f16* __restrict__ woh, f16* __restrict__ xh,
       int doX)
{
  const int NWQ = 3 * D_ * D_ / 4, NWO = D_ * D_ / 4, NX = B_ * S_ * D_ / 4;
  const int n = NWQ + NWO + (doX ? NX : 0);
  for (int i = blockIdx.x * 256 + threadIdx.x; i < n; i += gridDim.x * 256) {
    const float* src; f16* dst; int j;
    if (i < NWQ)            { src = wq; dst = wqh; j = i; }
    else if (i < NWQ + NWO) { src = wo; dst = woh; j = i - NWQ; }
    else                    { src = x;  dst = xh;  j = i - NWQ - NWO; }
    float4 v = ((const float4*)src)[j];
    f16x4 h = {(f16)v.x, (f16)v.y, (f16)v.z, (f16)v.w};
    ((f16x4*)dst)[j] = h;
  }
}

// ---------------------------------------------------------------------------
// Kernel 1: qkv = x @ w_qkv^T + RoPE epilogue.
// r5/r6-proven K-loop (BK=64, stage -> barrier -> 32 MFMA -> barrier),
// single change: LDS rows padded to stride 72 (conflict-free fragment reads).
// ---------------------------------------------------------------------------
template <bool XF16>
__global__ void __launch_bounds__(256)
k_qkv3(const float* __restrict__ xf, const f16* __restrict__ xh,
       const f16* __restrict__ wqh,
       f16* __restrict__ Qb, f16* __restrict__ Kb, f16* __restrict__ Vt)
{
  __shared__ __align__(16) f16 As[128 * PS];
  __shared__ __align__(16) f16 Bs[128 * PS];
  const int t = threadIdx.x;
  const int w = t >> 6;
  const int lane = t & 63;
  const int ll = lane & 15;
  const int quad = lane >> 4;
  const int wm = w >> 1, wn = w & 1;
  const int row0 = blockIdx.y * 128;
  const int col0 = blockIdx.x * 128;

  const f32x4 fz = {0.f, 0.f, 0.f, 0.f};
  f32x4 acc[4][4];
#pragma unroll
  for (int i = 0; i < 4; ++i)
#pragma unroll
    for (int j = 0; j < 4; ++j) acc[i][j] = fz;

  const int ldr = t >> 3;        // 0..31
  const int ldk = (t & 7) * 8;   // 0,8,..,56
  const float* gaf = xf  + (size_t)(row0 + ldr) * D_ + ldk;
  const f16*   gah = xh  + (size_t)(row0 + ldr) * D_ + ldk;
  const f16*   gb  = wqh + (size_t)(col0 + ldr) * D_ + ldk;

  for (int kt = 0; kt < D_; kt += 64) {
    f16x8 ra[4], rb[4];
#pragma unroll
    for (int i = 0; i < 4; ++i) {
      ra[i] = XF16 ? *(const f16x8*)(gah + (size_t)i * 32 * D_ + kt)
                   : cvt8(gaf + (size_t)i * 32 * D_ + kt);
      rb[i] = *(const f16x8*)(gb + (size_t)i * 32 * D_ + kt);
    }
    __syncthreads();   // previous iteration's LDS reads complete
#pragma unroll
    for (int i = 0; i < 4; ++i) {
      *(f16x8*)&As[(i * 32 + ldr) * PS + ldk] = ra[i];
      *(f16x8*)&Bs[(i * 32 + ldr) * PS + ldk] = rb[i];
    }
    __syncthreads();   // publish tile
#pragma unroll
    for (int kk = 0; kk < 64; kk += 32) {
      f16x8 a[4], b[4];
#pragma unroll
      for (int mt = 0; mt < 4; ++mt)
        a[mt] = *(const f16x8*)&As[(wm * 64 + mt * 16 + ll) * PS + kk + quad * 8];
#pragma unroll
      for (int nt = 0; nt < 4; ++nt)
        b[nt] = *(const f16x8*)&Bs[(wn * 64 + nt * 16 + ll) * PS + kk + quad * 8];
#pragma unroll
      for (int mt = 0; mt < 4; ++mt)
#pragma unroll
        for (int nt = 0; nt < 4; ++nt)
          acc[mt][nt] = __builtin_amdgcn_mfma_f32_16x16x32_f16(
              a[mt], b[nt], acc[mt][nt], 0, 0, 0);
    }
  }

  // Epilogue (verified r4-r7). C/D layout: col = ll, row = quad*4 + r.
  const int h3 = (col0 >> 6) + wn;
  if (h3 < 32) {
    f16* dst = (h3 < 16) ? Qb : Kb;
    const int h = (h3 < 16) ? h3 : h3 - 16;
    const float th0 = exp2f(-(float)ll * L2_10000_DIV32);
    const float th1 = exp2f(-(float)(16 + ll) * L2_10000_DIV32);
#pragma unroll
    for (int mt = 0; mt < 4; ++mt) {
#pragma unroll
      for (int r = 0; r < 4; ++r) {
        const int row = row0 + wm * 64 + mt * 16 + quad * 4 + r;
        const int b = row >> 11;
        const int p = row & (S_ - 1);
        f16* base = dst + ((size_t)(b * H_ + h) * S_ + p) * HD_;
        const float fp = (float)p;
        float s0, c0, s1, c1;
        sincosf(fp * th0, &s0, &c0);
        sincosf(fp * th1, &s1, &c1);
        {
          float x1 = acc[mt][0][r], x2 = acc[mt][2][r];
          base[ll]      = (f16)fin(x1 * c0 - x2 * s0);
          base[ll + 32] = (f16)fin(x2 * c0 + x1 * s0);
        }
        {
          float x1 = acc[mt][1][r], x2 = acc[mt][3][r];
          base[16 + ll]      = (f16)fin(x1 * c1 - x2 * s1);
          base[16 + ll + 32] = (f16)fin(x2 * c1 + x1 * s1);
        }
      }
    }
  } else {
    const int hv = h3 - 32;
#pragma unroll
    for (int mt = 0; mt < 4; ++mt)
#pragma unroll
      for (int nt = 0; nt < 4; ++nt)
#pragma unroll
        for (int r = 0; r < 4; ++r) {
          const int row = row0 + wm * 64 + mt * 16 + quad * 4 + r;
          const int b = row >> 11;
          const int p = row & (S_ - 1);
          const int dd = nt * 16 + ll;
          Vt[((size_t)(b * H_ + hv) * HD_ + dd) * S_ + p] = (f16)fin(acc[mt][nt][r]);
        }
  }
}

// ---------------------------------------------------------------------------
// k_attn2: causal flash attention (r5/r6, verified). O in place over Qb.
// ---------------------------------------------------------------------------
__device__ __forceinline__ void softmax_tile(
    f32x4 sc[4], bool diag, int qloc, int ll, int quad,
    float& mrun, float& lrun, float& alpha, f16* Pt)
{
  float pm = -3.0e4f;
#pragma unroll
  for (int nt = 0; nt < 4; ++nt)
#pragma unroll
    for (int r = 0; r < 4; ++r) {
      float s = sc[nt][r];
      s = (s == s) ? s : -3.0e4f;
      if (diag && (nt * 16 + quad * 4 + r) > qloc) s = -3.0e4f;
      sc[nt][r] = s;
      pm = fmaxf(pm, s);
    }
  pm = fmaxf(pm, __shfl_xor(pm, 16));
  pm = fmaxf(pm, __shfl_xor(pm, 32));
  const float mn = fmaxf(mrun, pm);
  alpha = exp2f(mrun - mn);
  mrun = mn;
  float ps = 0.f;
#pragma unroll
  for (int nt = 0; nt < 4; ++nt) {
    f16x4 pk;
#pragma unroll
    for (int r = 0; r < 4; ++r) {
      float p = exp2f(sc[nt][r] - mn);
      ps += p;
      pk[r] = (f16)p;
    }
    *(f16x4*)&Pt[ll * PS + nt * 16 + quad * 4] = pk;
  }
  ps += __shfl_xor(ps, 16);
  ps += __shfl_xor(ps, 32);
  lrun = lrun * alpha + ps;
}

__device__ __forceinline__ void write_o(
    f32x4 acco[4], float lrun, f16* Pt, int ll, int quad, int w,
    int qt, size_t bh, f16* Ob)
{
  const float inv = 1.0f / fmaxf(lrun, 1e-30f);
#pragma unroll
  for (int dg = 0; dg < 4; ++dg) {
    f16x4 ov;
#pragma unroll
    for (int r = 0; r < 4; ++r) ov[r] = (f16)fin(acco[dg][r] * inv);
    *(f16x4*)&Pt[ll * PS + dg * 16 + quad * 4] = ov;
  }
#pragma unroll
  for (int s2 = 0; s2 < 2; ++s2) {
    f16x8 o = *(const f16x8*)&Pt[ll * PS + (quad + 4 * s2) * 8];
    const size_t row = bh * S_ + qt * 64 + w * 16 + ll;
    *(f16x8*)&Ob[row * HD_ + (quad + 4 * s2) * 8] = o;
  }
}

__global__ void __launch_bounds__(256, 2)
k_attn2(const f16* Qb, const f16* __restrict__ Kb,
        const f16* __restrict__ Vt, f16* Ob)
{
  __shared__ __align__(16) f16 Qs[128 * PS];
  __shared__ __align__(16) f16 Ks[2][64 * PS];
  __shared__ __align__(16) f16 Vs[2][64 * PS];
  __shared__ __align__(16) f16 Ps[4][16 * PS];

  const int t = threadIdx.x;
  const int w = t >> 6;
  const int lane = t & 63;
  const int ll = lane & 15;
  const int quad = lane >> 4;
  const int qtA = blockIdx.x;
  const int qtB = 31 - qtA;
  const int h = blockIdx.y;
  const int b = blockIdx.z;
  const size_t bh = (size_t)b * H_ + h;
  const f16* Qg = Qb + bh * S_ * HD_;
  const f16* Kg = Kb + bh * S_ * HD_;
  const f16* Vg = Vt + bh * HD_ * S_;

  {
    const int r = t >> 1;
    const int c0 = (t & 1) * 32;
    const int grow = (r < 64) ? (qtA * 64 + r) : (qtB * 64 + r - 64);
    const f16 hsc = (f16)(0.125f * LOG2E);
#pragma unroll
    for (int j = 0; j < 4; ++j) {
      f16x8 v = *(const f16x8*)(Qg + (size_t)grow * HD_ + c0 + j * 8);
#pragma unroll
      for (int e = 0; e < 8; ++e) v[e] *= hsc;
      *(f16x8*)&Qs[r * PS + c0 + j * 8] = v;
    }
  }
  {
    const int r = t >> 2;
    const int c = (t & 3) * 16;
    f16x8 a0 = *(const f16x8*)(Kg + (size_t)r * HD_ + c);
    f16x8 a1 = *(const f16x8*)(Kg + (size_t)r * HD_ + c + 8);
    f16x8 b0 = *(const f16x8*)(Vg + (size_t)r * S_ + c);
    f16x8 b1 = *(const f16x8*)(Vg + (size_t)r * S_ + c + 8);
    *(f16x8*)&Ks[0][r * PS + c]     = a0;
    *(f16x8*)&Ks[0][r * PS + c + 8] = a1;
    *(f16x8*)&Vs[0][r * PS + c]     = b0;
    *(f16x8*)&Vs[0][r * PS + c + 8] = b1;
  }
  __syncthreads();

  const f32x4 fz = {0.f, 0.f, 0.f, 0.f};
  f32x4 accoA[4], accoB[4];
#pragma unroll
  for (int i = 0; i < 4; ++i) { accoA[i] = fz; accoB[i] = fz; }
  float mA = -3.0e4f, lA = 0.f, mB = -3.0e4f, lB = 0.f;
  const int qloc = w * 16 + ll;
  f16* Pt = &Ps[w][0];

  for (int kt = 0; kt <= qtB; ++kt) {
    const int cur = kt & 1;
    const bool pre = (kt < qtB);
    const int sr = t >> 2, scc = (t & 3) * 16;
    f16x8 nk0, nk1, nv0, nv1;
    if (pre) {
      const int kn = (kt + 1) * 64;
      nk0 = *(const f16x8*)(Kg + (size_t)(kn + sr) * HD_ + scc);
      nk1 = *(const f16x8*)(Kg + (size_t)(kn + sr) * HD_ + scc + 8);
      nv0 = *(const f16x8*)(Vg + (size_t)sr * S_ + kn + scc);
      nv1 = *(const f16x8*)(Vg + (size_t)sr * S_ + kn + scc + 8);
    }
    const f16* Kc = Ks[cur];
    const f16* Vc = Vs[cur];
    const bool doA = (kt <= qtA);

    f16x8 ak[2][4];
#pragma unroll
    for (int k2 = 0; k2 < 2; ++k2)
#pragma unroll
      for (int nt = 0; nt < 4; ++nt)
        ak[k2][nt] = *(const f16x8*)&Kc[(nt * 16 + ll) * PS + k2 * 32 + quad * 8];

    f32x4 sB[4] = {fz, fz, fz, fz};
#pragma unroll
    for (int k2 = 0; k2 < 2; ++k2) {
      f16x8 bq = *(const f16x8*)&Qs[(64 + w * 16 + ll) * PS + k2 * 32 + quad * 8];
#pragma unroll
      for (int nt = 0; nt < 4; ++nt)
        sB[nt] = __builtin_amdgcn_mfma_f32_16x16x32_f16(ak[k2][nt], bq, sB[nt], 0, 0, 0);
    }
    f32x4 sA[4] = {fz, fz, fz, fz};
    if (doA) {
#pragma unroll
      for (int k2 = 0; k2 < 2; ++k2) {
        f16x8 bq = *(const f16x8*)&Qs[(w * 16 + ll) * PS + k2 * 32 + quad * 8];
#pragma unroll
        for (int nt = 0; nt < 4; ++nt)
          sA[nt] = __builtin_amdgcn_mfma_f32_16x16x32_f16(ak[k2][nt], bq, sA[nt], 0, 0, 0);
      }
    }

    f16x8 av[2][4];
#pragma unroll
    for (int k2 = 0; k2 < 2; ++k2)
#pragma unroll
      for (int dg = 0; dg < 4; ++dg)
        av[k2][dg] = *(const f16x8*)&Vc[(dg * 16 + ll) * PS + k2 * 32 + quad * 8];

    float alpha;
    if (doA) {
      softmax_tile(sA, kt == qtA, qloc, ll, quad, mA, lA, alpha, Pt);
#pragma unroll
      for (int dg = 0; dg < 4; ++dg)
#pragma unroll
        for (int r = 0; r < 4; ++r) accoA[dg][r] *= alpha;
#pragma unroll
      for (int k2 = 0; k2 < 2; ++k2) {
        f16x8 bp = *(const f16x8*)&Pt[ll * PS + k2 * 32 + quad * 8];
#pragma unroll
        for (int dg = 0; dg < 4; ++dg)
          accoA[dg] = __builtin_amdgcn_mfma_f32_16x16x32_f16(av[k2][dg], bp, accoA[dg], 0, 0, 0);
      }
    }
    {
      softmax_tile(sB, kt == qtB, qloc, ll, quad, mB, lB, alpha, Pt);
#pragma unroll
      for (int dg = 0; dg < 4; ++dg)
#pragma unroll
        for (int r = 0; r < 4; ++r) accoB[dg][r] *= alpha;
#pragma unroll
      for (int k2 = 0; k2 < 2; ++k2) {
        f16x8 bp = *(const f16x8*)&Pt[ll * PS + k2 * 32 + quad * 8];
#pragma unroll
        for (int dg = 0; dg < 4; ++dg)
          accoB[dg] = __builtin_amdgcn_mfma_f32_16x16x32_f16(av[k2][dg], bp, accoB[dg], 0, 0, 0);
      }
    }

    if (pre) {
      *(f16x8*)&Ks[1 - cur][sr * PS + scc]     = nk0;
      *(f16x8*)&Ks[1 - cur][sr * PS + scc + 8] = nk1;
      *(f16x8*)&Vs[1 - cur][sr * PS + scc]     = nv0;
      *(f16x8*)&Vs[1 - cur][sr * PS + scc + 8] = nv1;
    }
    __syncthreads();
  }

  write_o(accoA, lA, Pt, ll, quad, w, qtA, bh, Ob);
  write_o(accoB, lB, Pt, ll, quad, w, qtB, bh, Ob);
}

// ---------------------------------------------------------------------------
// Kernel 3: out = O @ w_out^T + b_out. 64x128 tile (512 blocks -> 2/CU for
// cross-block latency hiding), BK=64 2-barrier loop, padded LDS (PS=72).
// A = O (f16, B,H,S,HD layout; BK=64 spans exactly one head).
// ---------------------------------------------------------------------------
__global__ void __launch_bounds__(256)
k_out3(const f16* __restrict__ Ob, const f16* __restrict__ Wh,
       const float* __restrict__ bias, float* __restrict__ out)
{
  __shared__ __align__(16) f16 As[64 * PS];
  __shared__ __align__(16) f16 Bs[128 * PS];
  const int t = threadIdx.x;
  const int w = t >> 6;
  const int lane = t & 63;
  const int ll = lane & 15;
  const int quad = lane >> 4;
  const int wm = w >> 1, wn = w & 1;     // wave tile: 32 (m) x 64 (n)
  const int row0 = blockIdx.y * 64;
  const int col0 = blockIdx.x * 128;
  const int bb = row0 >> 11;             // batch (64-row tile never crosses b)
  const int s0 = row0 & (S_ - 1);

  const f32x4 fz = {0.f, 0.f, 0.f, 0.f};
  f32x4 acc[2][4];
#pragma unroll
  for (int i = 0; i < 2; ++i)
#pragma unroll
    for (int j = 0; j < 4; ++j) acc[i][j] = fz;

  const int ldr = t >> 3;
  const int ldk = (t & 7) * 8;
  const f16* gb = Wh + (size_t)(col0 + ldr) * D_ + ldk;

  for (int kt = 0; kt < 16; ++kt) {      // head index = kt (BK = 64 = HD)
    const f16* ga = Ob + (((size_t)(bb * H_ + kt)) * S_ + s0 + ldr) * HD_ + ldk;
    f16x8 ra[2], rb[4];
#pragma unroll
    for (int i = 0; i < 2; ++i)
      ra[i] = *(const f16x8*)(ga + (size_t)i * 32 * HD_);
#pragma unroll
    for (int i = 0; i < 4; ++i)
      rb[i] = *(const f16x8*)(gb + (size_t)i * 32 * D_ + kt * 64);
    __syncthreads();
#pragma unroll
    for (int i = 0; i < 2; ++i)
      *(f16x8*)&As[(i * 32 + ldr) * PS + ldk] = ra[i];
#pragma unroll
    for (int i = 0; i < 4; ++i)
      *(f16x8*)&Bs[(i * 32 + ldr) * PS + ldk] = rb[i];
    __syncthreads();
#pragma unroll
    for (int kk = 0; kk < 64; kk += 32) {
      f16x8 a[2], b[4];
#pragma unroll
      for (int mt = 0; mt < 2; ++mt)
        a[mt] = *(const f16x8*)&As[(wm * 32 + mt * 16 + ll) * PS + kk + quad * 8];
#pragma unroll
      for (int nt = 0; nt < 4; ++nt)
        b[nt] = *(const f16x8*)&Bs[(wn * 64 + nt * 16 + ll) * PS + kk + quad * 8];
#pragma unroll
      for (int mt = 0; mt < 2; ++mt)
#pragma unroll
        for (int nt = 0; nt < 4; ++nt)
          acc[mt][nt] = __builtin_amdgcn_mfma_f32_16x16x32_f16(
              a[mt], b[nt], acc[mt][nt], 0, 0, 0);
    }
  }

#pragma unroll
  for (int mt = 0; mt < 2; ++mt)
#pragma unroll
    for (int r = 0; r < 4; ++r) {
      const int row = row0 + wm * 32 + mt * 16 + quad * 4 + r;
#pragma unroll
      for (int nt = 0; nt < 4; ++nt) {
        const int col = col0 + wn * 64 + nt * 16 + ll;
        out[(size_t)row * D_ + col] = fin(acc[mt][nt][r] + bias[col]);
      }
    }
}

// ---------------------------------------------------------------------------
extern "C" void kernel_launch(void* const* d_in, const int* in_sizes, int n_in,
                              void* d_out, int out_size, void* d_ws, size_t ws_size,
                              hipStream_t stream) {
  const float* x    = (const float*)d_in[0];
  const float* wqkv = (const float*)d_in[1];
  const float* wout = (const float*)d_in[2];
  const float* bout = (const float*)d_in[3];
  float* out = (float*)d_out;

  // ws: wqkvh 6M | Qb/O 8M | Kb 8M | Vt 8M | woh 2M | xh 8M (if big ws)
  char* ws = (char*)d_ws;
  f16* wqh = (f16*)(ws);
  f16* Qb  = (f16*)(ws + 6291456);
  f16* Kb  = (f16*)(ws + 14680064);
  f16* Vt  = (f16*)(ws + 23068672);
  f16* woh = (f16*)(ws + 31457280);
  const bool bigws = ws_size >= (size_t)41943040;
  f16* xh  = (f16*)(ws + 33554432);

  k_cvt3<<<2048, 256, 0, stream>>>(wqkv, wout, x, wqh, woh, xh, bigws ? 1 : 0);
  if (bigws)
    k_qkv3<true><<<dim3(3 * D_ / 128, (B_ * S_) / 128), 256, 0, stream>>>(
        x, xh, wqh, Qb, Kb, Vt);
  else
    k_qkv3<false><<<dim3(3 * D_ / 128, (B_ * S_) / 128), 256, 0, stream>>>(
        x, xh, wqh, Qb, Kb, Vt);
  k_attn2<<<dim3(16, H_, B_), 256, 0, stream>>>(Qb, Kb, Vt, Qb /* O in place */);
  k_out3<<<dim3(D_ / 128, (B_ * S_) / 64), 256, 0, stream>>>(
      Qb, woh, bout, out);
}

// Round 9
// 185.681 us; speedup vs baseline: 1.5205x; 1.0521x over previous
//
#include <hip/hip_runtime.h>
#include <hip/hip_fp16.h>
#include <math.h>

// Problem: B=2, S=2048, D=1024, H=16, HD=64, causal attention + RoPE.
// ALL inputs fp32 (reference dtypes), output fp32.
#define B_  2
#define S_  2048
#define D_  1024
#define H_  16
#define HD_ 64

typedef _Float16  f16;
typedef __attribute__((ext_vector_type(8))) _Float16 f16x8;
typedef __attribute__((ext_vector_type(4))) _Float16 f16x4;
typedef __attribute__((ext_vector_type(4))) float    f32x4;

#define LOG2E 1.4426950408889634f
#define L2_10000_DIV32 0.41524101186092029f  /* log2(10000)/32 */
#define PS 72   /* LDS row stride (f16): bank=(4*ll+4*quad)%32 -> uniform */

__device__ __forceinline__ float fin(float v) { return (v == v) ? v : 0.0f; }

__device__ __forceinline__ f16x8 cvt8(const float* p) {
  float4 a = *(const float4*)p;
  float4 b = *(const float4*)(p + 4);
  f16x8 h;
  h[0] = (f16)a.x; h[1] = (f16)a.y; h[2] = (f16)a.z; h[3] = (f16)a.w;
  h[4] = (f16)b.x; h[5] = (f16)b.y; h[6] = (f16)b.z; h[7] = (f16)b.w;
  return h;
}

// ---------------------------------------------------------------------------
// Kernel 0: one-shot fp32 -> f16 conversion of weights (and x when ws allows).
// ---------------------------------------------------------------------------
__global__ void __launch_bounds__(256)
k_cvt3(const float* __restrict__ wq, const float* __restrict__ wo,
       const float* __restrict__ x,
       f16* __restrict__ wqh, f16* __restrict__ woh, f16* __restrict__ xh,
       int doX)
{
  const int NWQ = 3 * D_ * D_ / 4, NWO = D_ * D_ / 4, NX = B_ * S_ * D_ / 4;
  const int n = NWQ + NWO + (doX ? NX : 0);
  for (int i = blockIdx.x * 256 + threadIdx.x; i < n; i += gridDim.x * 256) {
    const float* src; f16* dst; int j;
    if (i < NWQ)            { src = wq; dst = wqh; j = i; }
    else if (i < NWQ + NWO) { src = wo; dst = woh; j = i - NWQ; }
    else                    { src = x;  dst = xh;  j = i - NWQ - NWO; }
    float4 v = ((const float4*)src)[j];
    f16x4 h = {(f16)v.x, (f16)v.y, (f16)v.z, (f16)v.w};
    ((f16x4*)dst)[j] = h;
  }
}

// ---------------------------------------------------------------------------
// Kernel 1: qkv = x @ w_qkv^T + RoPE epilogue. (r8, verified: BK=64,
// 2-barrier K-loop, PS=72 padded LDS)
// ---------------------------------------------------------------------------
template <bool XF16>
__global__ void __launch_bounds__(256)
k_qkv3(const float* __restrict__ xf, const f16* __restrict__ xh,
       const f16* __restrict__ wqh,
       f16* __restrict__ Qb, f16* __restrict__ Kb, f16* __restrict__ Vt)
{
  __shared__ __align__(16) f16 As[128 * PS];
  __shared__ __align__(16) f16 Bs[128 * PS];
  const int t = threadIdx.x;
  const int w = t >> 6;
  const int lane = t & 63;
  const int ll = lane & 15;
  const int quad = lane >> 4;
  const int wm = w >> 1, wn = w & 1;
  const int row0 = blockIdx.y * 128;
  const int col0 = blockIdx.x * 128;

  const f32x4 fz = {0.f, 0.f, 0.f, 0.f};
  f32x4 acc[4][4];
#pragma unroll
  for (int i = 0; i < 4; ++i)
#pragma unroll
    for (int j = 0; j < 4; ++j) acc[i][j] = fz;

  const int ldr = t >> 3;
  const int ldk = (t & 7) * 8;
  const float* gaf = xf  + (size_t)(row0 + ldr) * D_ + ldk;
  const f16*   gah = xh  + (size_t)(row0 + ldr) * D_ + ldk;
  const f16*   gb  = wqh + (size_t)(col0 + ldr) * D_ + ldk;

  for (int kt = 0; kt < D_; kt += 64) {
    f16x8 ra[4], rb[4];
#pragma unroll
    for (int i = 0; i < 4; ++i) {
      ra[i] = XF16 ? *(const f16x8*)(gah + (size_t)i * 32 * D_ + kt)
                   : cvt8(gaf + (size_t)i * 32 * D_ + kt);
      rb[i] = *(const f16x8*)(gb + (size_t)i * 32 * D_ + kt);
    }
    __syncthreads();
#pragma unroll
    for (int i = 0; i < 4; ++i) {
      *(f16x8*)&As[(i * 32 + ldr) * PS + ldk] = ra[i];
      *(f16x8*)&Bs[(i * 32 + ldr) * PS + ldk] = rb[i];
    }
    __syncthreads();
#pragma unroll
    for (int kk = 0; kk < 64; kk += 32) {
      f16x8 a[4], b[4];
#pragma unroll
      for (int mt = 0; mt < 4; ++mt)
        a[mt] = *(const f16x8*)&As[(wm * 64 + mt * 16 + ll) * PS + kk + quad * 8];
#pragma unroll
      for (int nt = 0; nt < 4; ++nt)
        b[nt] = *(const f16x8*)&Bs[(wn * 64 + nt * 16 + ll) * PS + kk + quad * 8];
#pragma unroll
      for (int mt = 0; mt < 4; ++mt)
#pragma unroll
        for (int nt = 0; nt < 4; ++nt)
          acc[mt][nt] = __builtin_amdgcn_mfma_f32_16x16x32_f16(
              a[mt], b[nt], acc[mt][nt], 0, 0, 0);
    }
  }

  const int h3 = (col0 >> 6) + wn;
  if (h3 < 32) {
    f16* dst = (h3 < 16) ? Qb : Kb;
    const int h = (h3 < 16) ? h3 : h3 - 16;
    const float th0 = exp2f(-(float)ll * L2_10000_DIV32);
    const float th1 = exp2f(-(float)(16 + ll) * L2_10000_DIV32);
#pragma unroll
    for (int mt = 0; mt < 4; ++mt) {
#pragma unroll
      for (int r = 0; r < 4; ++r) {
        const int row = row0 + wm * 64 + mt * 16 + quad * 4 + r;
        const int b = row >> 11;
        const int p = row & (S_ - 1);
        f16* base = dst + ((size_t)(b * H_ + h) * S_ + p) * HD_;
        const float fp = (float)p;
        float s0, c0, s1, c1;
        sincosf(fp * th0, &s0, &c0);
        sincosf(fp * th1, &s1, &c1);
        {
          float x1 = acc[mt][0][r], x2 = acc[mt][2][r];
          base[ll]      = (f16)fin(x1 * c0 - x2 * s0);
          base[ll + 32] = (f16)fin(x2 * c0 + x1 * s0);
        }
        {
          float x1 = acc[mt][1][r], x2 = acc[mt][3][r];
          base[16 + ll]      = (f16)fin(x1 * c1 - x2 * s1);
          base[16 + ll + 32] = (f16)fin(x2 * c1 + x1 * s1);
        }
      }
    }
  } else {
    const int hv = h3 - 32;
#pragma unroll
    for (int mt = 0; mt < 4; ++mt)
#pragma unroll
      for (int nt = 0; nt < 4; ++nt)
#pragma unroll
        for (int r = 0; r < 4; ++r) {
          const int row = row0 + wm * 64 + mt * 16 + quad * 4 + r;
          const int b = row >> 11;
          const int p = row & (S_ - 1);
          const int dd = nt * 16 + ll;
          Vt[((size_t)(b * H_ + hv) * HD_ + dd) * S_ + p] = (f16)fin(acc[mt][nt][r]);
        }
  }
}

// ---------------------------------------------------------------------------
// k_attn3: causal flash attention (transposed, paired q-tiles). Changes vs
// r8: Q fragments held in REGISTERS (no Qs LDS -> 45 KB, 3 blocks/CU),
// softmax slimmed (no sanitize, diag-mask hoisted, max seeded with mrun).
// O in place over Qb (block reads Q once up-front, writes same rows at end).
// ---------------------------------------------------------------------------
__device__ __forceinline__ void softmax_tile(
    f32x4 sc[4], bool diag, int qloc, int ll, int quad,
    float& mrun, float& lrun, float& alpha, f16* Pt)
{
  if (diag) {
#pragma unroll
    for (int nt = 0; nt < 4; ++nt)
#pragma unroll
      for (int r = 0; r < 4; ++r)
        if ((nt * 16 + quad * 4 + r) > qloc) sc[nt][r] = -3.0e4f;
  }
  float pm = mrun;
#pragma unroll
  for (int nt = 0; nt < 4; ++nt)
#pragma unroll
    for (int r = 0; r < 4; ++r) pm = fmaxf(pm, sc[nt][r]);
  pm = fmaxf(pm, __shfl_xor(pm, 16));
  pm = fmaxf(pm, __shfl_xor(pm, 32));
  alpha = exp2f(mrun - pm);
  mrun = pm;
  float ps = 0.f;
#pragma unroll
  for (int nt = 0; nt < 4; ++nt) {
    f16x4 pk;
#pragma unroll
    for (int r = 0; r < 4; ++r) {
      float p = exp2f(sc[nt][r] - pm);
      ps += p;
      pk[r] = (f16)p;
    }
    *(f16x4*)&Pt[ll * PS + nt * 16 + quad * 4] = pk;
  }
  ps += __shfl_xor(ps, 16);
  ps += __shfl_xor(ps, 32);
  lrun = lrun * alpha + ps;
}

__device__ __forceinline__ void write_o(
    f32x4 acco[4], float lrun, f16* Pt, int ll, int quad, int w,
    int qt, size_t bh, f16* Ob)
{
  const float inv = 1.0f / fmaxf(lrun, 1e-30f);
#pragma unroll
  for (int dg = 0; dg < 4; ++dg) {
    f16x4 ov;
#pragma unroll
    for (int r = 0; r < 4; ++r) ov[r] = (f16)fin(acco[dg][r] * inv);
    *(f16x4*)&Pt[ll * PS + dg * 16 + quad * 4] = ov;
  }
#pragma unroll
  for (int s2 = 0; s2 < 2; ++s2) {
    f16x8 o = *(const f16x8*)&Pt[ll * PS + (quad + 4 * s2) * 8];
    const size_t row = bh * S_ + qt * 64 + w * 16 + ll;
    *(f16x8*)&Ob[row * HD_ + (quad + 4 * s2) * 8] = o;
  }
}

__global__ void __launch_bounds__(256, 3)
k_attn3(const f16* Qb, const f16* __restrict__ Kb,
        const f16* __restrict__ Vt, f16* Ob)
{
  __shared__ __align__(16) f16 Ks[2][64 * PS];   // 18 KB
  __shared__ __align__(16) f16 Vs[2][64 * PS];   // 18 KB
  __shared__ __align__(16) f16 Ps[4][16 * PS];   //  9 KB

  const int t = threadIdx.x;
  const int w = t >> 6;
  const int lane = t & 63;
  const int ll = lane & 15;
  const int quad = lane >> 4;
  const int qtA = blockIdx.x;          // 0..15
  const int qtB = 31 - qtA;            // 16..31 (uniform 33 tiles/block)
  const int h = blockIdx.y;
  const int b = blockIdx.z;
  const size_t bh = (size_t)b * H_ + h;
  const f16* Qg = Qb + bh * S_ * HD_;
  const f16* Kg = Kb + bh * S_ * HD_;
  const f16* Vg = Vt + bh * HD_ * S_;

  // Q fragments in registers (B-operand layout: row = q, col = quad*8..).
  f16x8 bqA[2], bqB[2];
  {
    const f16 hsc = (f16)(0.125f * LOG2E);
#pragma unroll
    for (int k2 = 0; k2 < 2; ++k2) {
      bqA[k2] = *(const f16x8*)(Qg + (size_t)(qtA * 64 + w * 16 + ll) * HD_ + k2 * 32 + quad * 8);
      bqB[k2] = *(const f16x8*)(Qg + (size_t)(qtB * 64 + w * 16 + ll) * HD_ + k2 * 32 + quad * 8);
#pragma unroll
      for (int e = 0; e < 8; ++e) { bqA[k2][e] *= hsc; bqB[k2][e] *= hsc; }
    }
  }
  // Stage K/V tile 0 -> buf 0.
  {
    const int r = t >> 2;
    const int c = (t & 3) * 16;
    f16x8 a0 = *(const f16x8*)(Kg + (size_t)r * HD_ + c);
    f16x8 a1 = *(const f16x8*)(Kg + (size_t)r * HD_ + c + 8);
    f16x8 b0 = *(const f16x8*)(Vg + (size_t)r * S_ + c);
    f16x8 b1 = *(const f16x8*)(Vg + (size_t)r * S_ + c + 8);
    *(f16x8*)&Ks[0][r * PS + c]     = a0;
    *(f16x8*)&Ks[0][r * PS + c + 8] = a1;
    *(f16x8*)&Vs[0][r * PS + c]     = b0;
    *(f16x8*)&Vs[0][r * PS + c + 8] = b1;
  }
  __syncthreads();

  const f32x4 fz = {0.f, 0.f, 0.f, 0.f};
  f32x4 accoA[4], accoB[4];
#pragma unroll
  for (int i = 0; i < 4; ++i) { accoA[i] = fz; accoB[i] = fz; }
  float mA = -3.0e4f, lA = 0.f, mB = -3.0e4f, lB = 0.f;
  const int qloc = w * 16 + ll;
  f16* Pt = &Ps[w][0];

  for (int kt = 0; kt <= qtB; ++kt) {
    const int cur = kt & 1;
    const bool pre = (kt < qtB);
    const int sr = t >> 2, scc = (t & 3) * 16;
    f16x8 nk0, nk1, nv0, nv1;
    if (pre) {   // register prefetch of next K/V tile (hidden by compute)
      const int kn = (kt + 1) * 64;
      nk0 = *(const f16x8*)(Kg + (size_t)(kn + sr) * HD_ + scc);
      nk1 = *(const f16x8*)(Kg + (size_t)(kn + sr) * HD_ + scc + 8);
      nv0 = *(const f16x8*)(Vg + (size_t)sr * S_ + kn + scc);
      nv1 = *(const f16x8*)(Vg + (size_t)sr * S_ + kn + scc + 8);
    }
    const f16* Kc = Ks[cur];
    const f16* Vc = Vs[cur];
    const bool doA = (kt <= qtA);

    f16x8 ak[2][4];
#pragma unroll
    for (int k2 = 0; k2 < 2; ++k2)
#pragma unroll
      for (int nt = 0; nt < 4; ++nt)
        ak[k2][nt] = *(const f16x8*)&Kc[(nt * 16 + ll) * PS + k2 * 32 + quad * 8];

    f32x4 sB[4] = {fz, fz, fz, fz};
#pragma unroll
    for (int k2 = 0; k2 < 2; ++k2)
#pragma unroll
      for (int nt = 0; nt < 4; ++nt)
        sB[nt] = __builtin_amdgcn_mfma_f32_16x16x32_f16(ak[k2][nt], bqB[k2], sB[nt], 0, 0, 0);
    f32x4 sA[4] = {fz, fz, fz, fz};
    if (doA) {
#pragma unroll
      for (int k2 = 0; k2 < 2; ++k2)
#pragma unroll
        for (int nt = 0; nt < 4; ++nt)
          sA[nt] = __builtin_amdgcn_mfma_f32_16x16x32_f16(ak[k2][nt], bqA[k2], sA[nt], 0, 0, 0);
    }

    f16x8 av[2][4];
#pragma unroll
    for (int k2 = 0; k2 < 2; ++k2)
#pragma unroll
      for (int dg = 0; dg < 4; ++dg)
        av[k2][dg] = *(const f16x8*)&Vc[(dg * 16 + ll) * PS + k2 * 32 + quad * 8];

    float alpha;
    if (doA) {
      softmax_tile(sA, kt == qtA, qloc, ll, quad, mA, lA, alpha, Pt);
#pragma unroll
      for (int dg = 0; dg < 4; ++dg)
#pragma unroll
        for (int r = 0; r < 4; ++r) accoA[dg][r] *= alpha;
#pragma unroll
      for (int k2 = 0; k2 < 2; ++k2) {
        f16x8 bp = *(const f16x8*)&Pt[ll * PS + k2 * 32 + quad * 8];
#pragma unroll
        for (int dg = 0; dg < 4; ++dg)
          accoA[dg] = __builtin_amdgcn_mfma_f32_16x16x32_f16(av[k2][dg], bp, accoA[dg], 0, 0, 0);
      }
    }
    {
      softmax_tile(sB, kt == qtB, qloc, ll, quad, mB, lB, alpha, Pt);
#pragma unroll
      for (int dg = 0; dg < 4; ++dg)
#pragma unroll
        for (int r = 0; r < 4; ++r) accoB[dg][r] *= alpha;
#pragma unroll
      for (int k2 = 0; k2 < 2; ++k2) {
        f16x8 bp = *(const f16x8*)&Pt[ll * PS + k2 * 32 + quad * 8];
#pragma unroll
        for (int dg = 0; dg < 4; ++dg)
          accoB[dg] = __builtin_amdgcn_mfma_f32_16x16x32_f16(av[k2][dg], bp, accoB[dg], 0, 0, 0);
      }
    }

    if (pre) {
      *(f16x8*)&Ks[1 - cur][sr * PS + scc]     = nk0;
      *(f16x8*)&Ks[1 - cur][sr * PS + scc + 8] = nk1;
      *(f16x8*)&Vs[1 - cur][sr * PS + scc]     = nv0;
      *(f16x8*)&Vs[1 - cur][sr * PS + scc + 8] = nv1;
    }
    __syncthreads();
  }

  write_o(accoA, lA, Pt, ll, quad, w, qtA, bh, Ob);
  write_o(accoB, lB, Pt, ll, quad, w, qtB, bh, Ob);
}

// ---------------------------------------------------------------------------
// Kernel 3: out = O @ w_out^T + b_out. (r8, verified: 64x128 tile, PS=72)
// ---------------------------------------------------------------------------
__global__ void __launch_bounds__(256)
k_out3(const f16* __restrict__ Ob, const f16* __restrict__ Wh,
       const float* __restrict__ bias, float* __restrict__ out)
{
  __shared__ __align__(16) f16 As[64 * PS];
  __shared__ __align__(16) f16 Bs[128 * PS];
  const int t = threadIdx.x;
  const int w = t >> 6;
  const int lane = t & 63;
  const int ll = lane & 15;
  const int quad = lane >> 4;
  const int wm = w >> 1, wn = w & 1;
  const int row0 = blockIdx.y * 64;
  const int col0 = blockIdx.x * 128;
  const int bb = row0 >> 11;
  const int s0 = row0 & (S_ - 1);

  const f32x4 fz = {0.f, 0.f, 0.f, 0.f};
  f32x4 acc[2][4];
#pragma unroll
  for (int i = 0; i < 2; ++i)
#pragma unroll
    for (int j = 0; j < 4; ++j) acc[i][j] = fz;

  const int ldr = t >> 3;
  const int ldk = (t & 7) * 8;
  const f16* gb = Wh + (size_t)(col0 + ldr) * D_ + ldk;

  for (int kt = 0; kt < 16; ++kt) {
    const f16* ga = Ob + (((size_t)(bb * H_ + kt)) * S_ + s0 + ldr) * HD_ + ldk;
    f16x8 ra[2], rb[4];
#pragma unroll
    for (int i = 0; i < 2; ++i)
      ra[i] = *(const f16x8*)(ga + (size_t)i * 32 * HD_);
#pragma unroll
    for (int i = 0; i < 4; ++i)
      rb[i] = *(const f16x8*)(gb + (size_t)i * 32 * D_ + kt * 64);
    __syncthreads();
#pragma unroll
    for (int i = 0; i < 2; ++i)
      *(f16x8*)&As[(i * 32 + ldr) * PS + ldk] = ra[i];
#pragma unroll
    for (int i = 0; i < 4; ++i)
      *(f16x8*)&Bs[(i * 32 + ldr) * PS + ldk] = rb[i];
    __syncthreads();
#pragma unroll
    for (int kk = 0; kk < 64; kk += 32) {
      f16x8 a[2], b[4];
#pragma unroll
      for (int mt = 0; mt < 2; ++mt)
        a[mt] = *(const f16x8*)&As[(wm * 32 + mt * 16 + ll) * PS + kk + quad * 8];
#pragma unroll
      for (int nt = 0; nt < 4; ++nt)
        b[nt] = *(const f16x8*)&Bs[(wn * 64 + nt * 16 + ll) * PS + kk + quad * 8];
#pragma unroll
      for (int mt = 0; mt < 2; ++mt)
#pragma unroll
        for (int nt = 0; nt < 4; ++nt)
          acc[mt][nt] = __builtin_amdgcn_mfma_f32_16x16x32_f16(
              a[mt], b[nt], acc[mt][nt], 0, 0, 0);
    }
  }

#pragma unroll
  for (int mt = 0; mt < 2; ++mt)
#pragma unroll
    for (int r = 0; r < 4; ++r) {
      const int row = row0 + wm * 32 + mt * 16 + quad * 4 + r;
#pragma unroll
      for (int nt = 0; nt < 4; ++nt) {
        const int col = col0 + wn * 64 + nt * 16 + ll;
        out[(size_t)row * D_ + col] = fin(acc[mt][nt][r] + bias[col]);
      }
    }
}

// ---------------------------------------------------------------------------
extern "C" void kernel_launch(void* const* d_in, const int* in_sizes, int n_in,
                              void* d_out, int out_size, void* d_ws, size_t ws_size,
                              hipStream_t stream) {
  const float* x    = (const float*)d_in[0];
  const float* wqkv = (const float*)d_in[1];
  const float* wout = (const float*)d_in[2];
  const float* bout = (const float*)d_in[3];
  float* out = (float*)d_out;

  // ws: wqkvh 6M | Qb/O 8M | Kb 8M | Vt 8M | woh 2M | xh 8M (if big ws)
  char* ws = (char*)d_ws;
  f16* wqh = (f16*)(ws);
  f16* Qb  = (f16*)(ws + 6291456);
  f16* Kb  = (f16*)(ws + 14680064);
  f16* Vt  = (f16*)(ws + 23068672);
  f16* woh = (f16*)(ws + 31457280);
  const bool bigws = ws_size >= (size_t)41943040;
  f16* xh  = (f16*)(ws + 33554432);

  k_cvt3<<<2048, 256, 0, stream>>>(wqkv, wout, x, wqh, woh, xh, bigws ? 1 : 0);
  if (bigws)
    k_qkv3<true><<<dim3(3 * D_ / 128, (B_ * S_) / 128), 256, 0, stream>>>(
        x, xh, wqh, Qb, Kb, Vt);
  else
    k_qkv3<false><<<dim3(3 * D_ / 128, (B_ * S_) / 128), 256, 0, stream>>>(
        x, xh, wqh, Qb, Kb, Vt);
  k_attn3<<<dim3(16, H_, B_), 256, 0, stream>>>(Qb, Kb, Vt, Qb /* O in place */);
  k_out3<<<dim3(D_ / 128, (B_ * S_) / 64), 256, 0, stream>>>(
      Qb, woh, bout, out);
}